// Round 2
// baseline (323.498 us; speedup 1.0000x reference)
//
#include <hip/hip_runtime.h>
#include <hip/hip_bf16.h>

// TreeRNN: K=8, DEPTH=7, N=299593, V=32000, X=H=O=128.
// bf16 MFMA 16x16x32, fp32 accumulate.
// Structure: h never touches HBM. Each level computes the 8-child sums of
// its own h tile (in LDS for the W_out GEMM) and writes one bf16 "childsum"
// row per parent; the parent level loads its U-GEMM A-fragments straight
// from that row. Embed-GEMM A-fragments load directly from a pre-converted
// bf16 emb table.
// This round: 32 rows per wave (two 16-row MFMA sub-tiles, 128-row blocks).
// Every B fragment is loaded once and used by TWO MFMAs -> B-fragment
// L1/L2 traffic and VMEM issue per row halve (leaf was streaming ~1 GB of
// B frags at 1 load : 1 mfma).
// Alignment fact: s_l - 1 = 8*s_{l-1}, so every 128-row block is exactly
// the children of 16 consecutive parents.

typedef __bf16 bf16x8 __attribute__((ext_vector_type(8)));
typedef float f32x4 __attribute__((ext_vector_type(4)));
typedef float f32x2 __attribute__((ext_vector_type(2)));
typedef unsigned short ushort8 __attribute__((ext_vector_type(8)));
typedef unsigned int uint2v __attribute__((ext_vector_type(2)));

#define NNODES 299593
#define NPAR   37449   // nodes 0..37448 have children

static __device__ __forceinline__ unsigned short f2bf(float f) {
  union { float f; unsigned int u; } v; v.f = f;
  unsigned int u = v.u;
  u += 0x7fff + ((u >> 16) & 1);   // RNE
  return (unsigned short)(u >> 16);
}

// pack 2 floats -> 2 bf16 in one dword (a -> low, b -> high)
static __device__ __forceinline__ unsigned int pk2bf(float a, float b) {
#if __has_builtin(__builtin_amdgcn_cvt_pk_bf16_f32)
  typedef __bf16 bf16x2 __attribute__((ext_vector_type(2)));
  union { bf16x2 v; unsigned int u; } c;
  c.v = __builtin_amdgcn_cvt_pk_bf16_f32(a, b);
  return c.u;
#else
  return (unsigned int)f2bf(a) | ((unsigned int)f2bf(b) << 16);
#endif
}

// tanh(x) = 1 - 2/(1+e^{2x})
static __device__ __forceinline__ float fast_tanh(float x) {
  float y = x * 2.885390081777927f;  // 2*log2(e)
#if __has_builtin(__builtin_amdgcn_exp2f)
  float e = __builtin_amdgcn_exp2f(y);
#else
  float e = __builtin_exp2f(y);
#endif
#if __has_builtin(__builtin_amdgcn_rcpf)
  float r = __builtin_amdgcn_rcpf(e + 1.0f);
#else
  float r = 1.0f / (e + 1.0f);
#endif
  return __builtin_fmaf(-2.0f, r, 1.0f);
}

// Swizzle W (128x128 row-major fp32) into B-fragment order for
// v_mfma_f32_16x16x32_bf16: frag f = ((kt*8+nt)*64 + lane)*8 + j
// holds W[kt*32 + (lane>>4)*8 + j][nt*16 + (lane&15)].
// Also converts emb (32000x128 fp32) -> bf16 once.
__global__ __launch_bounds__(256) void prep_kernel(
    const float* __restrict__ W_in, const float* __restrict__ U,
    const float* __restrict__ W_out, const float* __restrict__ emb,
    unsigned short* __restrict__ w_sw, unsigned short* __restrict__ emb_bf) {
  int t = blockIdx.x * 256 + threadIdx.x;
  if (blockIdx.x < 192) {              // 49152 weight elements
    int f = t;
    int m = f >> 14;
    int r = f & 16383;
    int j = r & 7;
    int lane = (r >> 3) & 63;
    int nt = (r >> 9) & 7;
    int kt = (r >> 12) & 3;
    int k = kt * 32 + ((lane >> 4) * 8) + j;
    int n = nt * 16 + (lane & 15);
    const float* W = (m == 0) ? W_in : (m == 1) ? U : W_out;
    w_sw[f] = f2bf(W[k * 128 + n]);
  } else {                              // 4,096,000 emb elements, 8 per thread
    size_t i = (size_t)(t - 49152) * 8;
    f32x4 v0 = *(const f32x4*)(emb + i);
    f32x4 v1 = *(const f32x4*)(emb + i + 4);
    union { ushort8 s; unsigned int u[4]; } w;
    w.u[0] = pk2bf(v0[0], v0[1]);
    w.u[1] = pk2bf(v0[2], v0[3]);
    w.u[2] = pk2bf(v1[0], v1[1]);
    w.u[3] = pk2bf(v1[2], v1[3]);
    *(ushort8*)(emb_bf + i) = w.s;
  }
}

// load a 16B bf16 A-fragment, zeroed when !nz (per-lane predicate)
static __device__ __forceinline__ bf16x8 ldz(const unsigned short* p, int nz) {
  union { bf16x8 b; unsigned int u[4]; } v;
  v.b = *(const bf16x8*)p;
  if (!nz) { v.u[0] = 0; v.u[1] = 0; v.u[2] = 0; v.u[3] = 0; }
  return v.b;
}

// one K-block of a 32x128 MFMA row-pair: 8 nt tiles, B frag loaded ONCE,
// used by both sub-tiles. bp already includes matrix offset + kt*4096 + lane*8.
static __device__ __forceinline__ void mfma8x2(
    f32x4 (&acc0)[8], f32x4 (&acc1)[8], bf16x8 a0, bf16x8 a1,
    const unsigned short* __restrict__ bp) {
#pragma unroll
  for (int nt = 0; nt < 8; ++nt) {
    bf16x8 b = *(const bf16x8*)(bp + nt * 512);
    acc0[nt] = __builtin_amdgcn_mfma_f32_16x16x32_bf16(a0, b, acc0[nt], 0, 0, 0);
    acc1[nt] = __builtin_amdgcn_mfma_f32_16x16x32_bf16(a1, b, acc1[nt], 0, 0, 0);
  }
}

template <bool LEAF>
static __device__ __forceinline__ void tile_body(
    const int* __restrict__ x, const int* __restrict__ mask,
    const unsigned short* __restrict__ emb_bf,
    const float* __restrict__ b_in, const float* __restrict__ b_out,
    const unsigned short* __restrict__ w_sw,
    unsigned short* __restrict__ cs, float* __restrict__ out,
    int e, int row0, unsigned short (*Abuf)[136], int tid) {
  const int lane = tid & 63;
  const int wave = tid >> 6;
  const int coll = lane & 15;
  const int quad = lane >> 4;

  // per-lane A rows: sub-tile 0 = wave*32+coll, sub-tile 1 = +16
  const int ga0 = row0 + wave * 32 + coll;
  const int ga1 = ga0 + 16;
  const int v0 = ga0 < e;
  const int v1 = ga1 < e;
  const int m0 = v0 ? mask[ga0] : 0;
  const int m1 = v1 ? mask[ga1] : 0;
  const int i0 = v0 ? x[ga0] * m0 : 0;
  const int i1 = v1 ? x[ga1] * m1 : 0;

  // ---- issue embed A-fragment loads up front (hide gather latency) ----
  const unsigned short* a0p = emb_bf + (size_t)i0 * 128 + quad * 8;
  const unsigned short* a1p = emb_bf + (size_t)i1 * 128 + quad * 8;
  bf16x8 e00 = ldz(a0p, m0),      e10 = ldz(a1p, m1);
  bf16x8 e01 = ldz(a0p + 32, m0), e11 = ldz(a1p + 32, m1);
  bf16x8 e02 = ldz(a0p + 64, m0), e12 = ldz(a1p + 64, m1);
  bf16x8 e03 = ldz(a0p + 96, m0), e13 = ldz(a1p + 96, m1);

  const unsigned short* bl = w_sw + lane * 8;

  f32x4 acc0[8], acc1[8];
#pragma unroll
  for (int nt = 0; nt < 8; ++nt) {
    acc0[nt] = (f32x4){0.f, 0.f, 0.f, 0.f};
    acc1[nt] = (f32x4){0.f, 0.f, 0.f, 0.f};
  }

  // ---- GEMM 1: emb @ W_in ----
  mfma8x2(acc0, acc1, e00, e10, bl);
  mfma8x2(acc0, acc1, e01, e11, bl + 4096);
  mfma8x2(acc0, acc1, e02, e12, bl + 8192);
  mfma8x2(acc0, acc1, e03, e13, bl + 12288);

  // ---- GEMM 2: childsum @ U (loads issued after ea regs die) ----
  if (!LEAF) {
    const unsigned short* c0p = cs + (size_t)ga0 * 128 + quad * 8;
    const unsigned short* c1p = cs + (size_t)ga1 * 128 + quad * 8;
    bf16x8 c00 = ldz(c0p, v0),      c10 = ldz(c1p, v1);
    bf16x8 c01 = ldz(c0p + 32, v0), c11 = ldz(c1p + 32, v1);
    bf16x8 c02 = ldz(c0p + 64, v0), c12 = ldz(c1p + 64, v1);
    bf16x8 c03 = ldz(c0p + 96, v0), c13 = ldz(c1p + 96, v1);
    mfma8x2(acc0, acc1, c00, c10, bl + 16384);
    mfma8x2(acc0, acc1, c01, c11, bl + 20480);
    mfma8x2(acc0, acc1, c02, c12, bl + 24576);
    mfma8x2(acc0, acc1, c03, c13, bl + 28672);
  }

  // ---- epilogue 1: + m*b_in, fast tanh; h -> LDS (wave-private) ----
  float binv[8];
#pragma unroll
  for (int nt = 0; nt < 8; ++nt) binv[nt] = b_in[nt * 16 + coll];

  auto epi = [&](f32x4 (&ac)[8], int sub) {
#pragma unroll
    for (int r2 = 0; r2 < 4; ++r2) {
      const int rowl = wave * 32 + sub * 16 + quad * 4 + r2;  // C: row=quad*4+reg
      const int grow = row0 + rowl;
      const float mval = (grow < e) ? (float)mask[grow] : 0.f;
#pragma unroll
      for (int nt = 0; nt < 8; ++nt) {
        float t = ac[nt][r2] + mval * binv[nt];
        Abuf[rowl][nt * 16 + coll] = f2bf(fast_tanh(t));
      }
    }
  };
  epi(acc0, 0);
  epi(acc1, 1);
  __builtin_amdgcn_wave_barrier();

  // ---- childsum production: wave's 32 rows = 4 complete parents ----
  // (row0-1 is divisible by 8 for every level; root tile row0==0 skips)
  if (row0 > 0) {
    const int j = lane >> 5;              // parent 0/1 within 16-row half
    const int c4 = (lane & 31) * 4;       // ushort col 0,4,...,124
#pragma unroll
    for (int sub = 0; sub < 2; ++sub) {
      const int pidx = wave * 4 + sub * 2 + j;       // parent 0..15 in tile
      const int childrow0 = row0 + pidx * 8;
      if (childrow0 < e) {
        const int lr0 = wave * 32 + sub * 16 + j * 8;
        f32x2 sA = {0.f, 0.f}, sB = {0.f, 0.f};
#pragma unroll
        for (int r = 0; r < 8; ++r) {     // children ascending: fixed fp32
          const unsigned int* pr =        // summation order
              (const unsigned int*)&Abuf[lr0 + r][c4];
          unsigned int u0 = pr[0], u1 = pr[1];
          union { unsigned int u; float f; } l0, h0, l1, h1;
          l0.u = u0 << 16; h0.u = u0 & 0xffff0000u;
          l1.u = u1 << 16; h1.u = u1 & 0xffff0000u;
          sA += (f32x2){l0.f, h0.f};
          sB += (f32x2){l1.f, h1.f};
        }
        uint2v w;
        w.x = pk2bf(sA[0], sA[1]);
        w.y = pk2bf(sB[0], sB[1]);
        const int p = ((row0 - 1) >> 3) + pidx;
        *(uint2v*)(cs + (size_t)p * 128 + c4) = w;
      }
    }
  }

  // ---- GEMM 3: out = h @ W_out + b_out (A frags transposed via LDS) ----
  f32x4 o0[8], o1[8];
#pragma unroll
  for (int nt = 0; nt < 8; ++nt) {
    o0[nt] = (f32x4){0.f, 0.f, 0.f, 0.f};
    o1[nt] = (f32x4){0.f, 0.f, 0.f, 0.f};
  }
  const unsigned short* ab0 = &Abuf[wave * 32][0] + coll * 136 + quad * 8;
  const unsigned short* ab1 = ab0 + 16 * 136;
#pragma unroll
  for (int kt = 0; kt < 4; ++kt) {
    bf16x8 a0 = *(const bf16x8*)(ab0 + kt * 32);
    bf16x8 a1 = *(const bf16x8*)(ab1 + kt * 32);
    mfma8x2(o0, o1, a0, a1, bl + 32768 + kt * 4096);
  }

  float boutv[8];
#pragma unroll
  for (int nt = 0; nt < 8; ++nt) boutv[nt] = b_out[nt * 16 + coll];

  auto st = [&](f32x4 (&oc)[8], int sub) {
#pragma unroll
    for (int r2 = 0; r2 < 4; ++r2) {
      const int rowl = wave * 32 + sub * 16 + quad * 4 + r2;
      const int grow = row0 + rowl;
      if (grow < e) {
#pragma unroll
        for (int nt = 0; nt < 8; ++nt)
          out[(size_t)grow * 128 + nt * 16 + coll] = oc[nt][r2] + boutv[nt];
      }
    }
  };
  st(o0, 0);
  st(o1, 1);
}

template <bool LEAF>
__global__ __launch_bounds__(256) void level_kernel(
    const int* __restrict__ x, const int* __restrict__ mask,
    const unsigned short* __restrict__ emb_bf, const float* __restrict__ b_in,
    const float* __restrict__ b_out, const unsigned short* __restrict__ w_sw,
    unsigned short* __restrict__ cs, float* __restrict__ out, int s, int e) {
  __shared__ __align__(16) unsigned short Abuf[128][136];
  tile_body<LEAF>(x, mask, emb_bf, b_in, b_out, w_sw, cs, out, e,
                  s + blockIdx.x * 128, Abuf, threadIdx.x);
}

// Levels 2 (rows 9..72), 1 (rows 1..8), 0 (row 0) in one block.
// __syncthreads between tiles: barrier's vmcnt(0) drain + L1 behavior
// (cs lines written here were never previously read this dispatch) makes
// the same-block global childsum RAW safe (verified passing in r0/r1).
__global__ __launch_bounds__(256) void tail_kernel(
    const int* __restrict__ x, const int* __restrict__ mask,
    const unsigned short* __restrict__ emb_bf, const float* __restrict__ b_in,
    const float* __restrict__ b_out, const unsigned short* __restrict__ w_sw,
    unsigned short* __restrict__ cs, float* __restrict__ out) {
  __shared__ __align__(16) unsigned short Abuf[128][136];
  tile_body<false>(x, mask, emb_bf, b_in, b_out, w_sw, cs, out, 73, 9, Abuf,
                   threadIdx.x);
  __syncthreads();
  tile_body<false>(x, mask, emb_bf, b_in, b_out, w_sw, cs, out, 9, 1, Abuf,
                   threadIdx.x);
  __syncthreads();
  tile_body<false>(x, mask, emb_bf, b_in, b_out, w_sw, cs, out, 1, 0, Abuf,
                   threadIdx.x);
}

extern "C" void kernel_launch(void* const* d_in, const int* in_sizes, int n_in,
                              void* d_out, int out_size, void* d_ws,
                              size_t ws_size, hipStream_t stream) {
  const int* x = (const int*)d_in[0];
  const int* mask = (const int*)d_in[1];
  // d_in[2] = children: implied (child rows of i are i*8+1..i*8+8)
  const float* emb = (const float*)d_in[3];
  const float* W_in = (const float*)d_in[4];
  const float* b_in = (const float*)d_in[5];
  const float* U = (const float*)d_in[6];
  const float* W_out = (const float*)d_in[7];
  const float* b_out = (const float*)d_in[8];
  float* out = (float*)d_out;

  // ws layout: emb bf16 [32000*128] | childsum bf16 [NPAR*128] | w_sw [3*16384]
  unsigned short* emb_bf = (unsigned short*)d_ws;
  unsigned short* cs = emb_bf + (size_t)32000 * 128;
  unsigned short* w_sw = cs + (size_t)NPAR * 128;

  prep_kernel<<<2192, 256, 0, stream>>>(W_in, U, W_out, emb, w_sw, emb_bf);

  // leaf level l=6: rows 37449..299592 -> childsum for parents 4681..37448
  level_kernel<true><<<2048, 256, 0, stream>>>(x, mask, emb_bf, b_in, b_out,
                                               w_sw, cs, out, 37449, 299593);
  // l=5
  level_kernel<false><<<256, 256, 0, stream>>>(x, mask, emb_bf, b_in, b_out,
                                               w_sw, cs, out, 4681, 37449);
  // l=4
  level_kernel<false><<<32, 256, 0, stream>>>(x, mask, emb_bf, b_in, b_out,
                                              w_sw, cs, out, 585, 4681);
  // l=3
  level_kernel<false><<<4, 256, 0, stream>>>(x, mask, emb_bf, b_in, b_out,
                                             w_sw, cs, out, 73, 585);
  // l=2,1,0 merged
  tail_kernel<<<1, 256, 0, stream>>>(x, mask, emb_bf, b_in, b_out, w_sw, cs,
                                     out);
}